// Round 1
// baseline (361.648 us; speedup 1.0000x reference)
//
#include <hip/hip_runtime.h>
#include <hip/hip_bf16.h>

// Problem constants: B=8, T=512, N=64, E=128, H=256, P=96
// Key identities used:
//   xe[b,n,t,e] = x_noD[b,n,t]*emb[e]  => rfft over t factorizes: xf = Xf (scalar) * emb
//   mlp(s*emb)  = piecewise-linear in s (256 breakpoints at -b1_h/u_h, u=emb@w1)
//   packed real-DFT (257 cos + 255 sin rows, K=512) is invertible =>
//     out[t,bn,e] = sum_k W[t,k] * Y'[k,bn,e],
//     Y' = softshrink(y(s)) + rfftpack(xn) + s*(1+emb)   (bias/xn folded spectrally)
//   flat@fw1 = sum_{k,e} Y' * M2[k,e,h],  M2[k,e,h] = sum_t W[t,k] fw1[t*128+e,h]
// Large-magnitude bias term s*(1+emb) handled in exact f32 via G[k,h]=sum_e(1+emb_e)M2.

typedef unsigned int uint;
typedef unsigned short ushort_t;
typedef __attribute__((ext_vector_type(4))) float f32x4;
typedef __attribute__((ext_vector_type(8))) short short8;

#define LAMBDA_ 0.001f
#define RSQRT512 0.044194173824159220f  // 1/sqrt(512)

__device__ __forceinline__ ushort_t f2bf(float f) {
    uint u = __float_as_uint(f);
    uint r = (u + 0x7FFFu + ((u >> 16) & 1u)) >> 16;
    return (ushort_t)r;
}
__device__ __forceinline__ float bf2f(ushort_t v) {
    return __uint_as_float(((uint)v) << 16);
}
__device__ __forceinline__ float leaky_(float v) { return v >= 0.f ? v : 0.01f * v; }

// ---------------- K0: transpose x [8][512][64] -> xT [512(bn)][512(t)] ----------------
__global__ __launch_bounds__(256) void k_transpose_x(const float* __restrict__ x, float* __restrict__ xT) {
    __shared__ float tile[32][33];
    int bid = blockIdx.x;             // 8 * 16 * 2 = 256 blocks
    int b = bid >> 5;
    int rem = bid & 31;
    int t0 = (rem >> 1) << 5;
    int n0 = (rem & 1) << 5;
    int tx = threadIdx.x & 31, ty = threadIdx.x >> 5;  // 32 x 8
    for (int i = 0; i < 4; ++i) {
        int tt = ty * 4 + i;
        tile[tt][tx] = x[(size_t)(b * 512 + t0 + tt) * 64 + n0 + tx];
    }
    __syncthreads();
    for (int i = 0; i < 4; ++i) {
        int nn = ty * 4 + i;
        xT[(size_t)(b * 64 + n0 + nn) * 512 + t0 + tx] = tile[tx][nn];
    }
}

// ---------------- K1: generate packed-DFT matrices ----------------
// D[t][k]  (f32): k<=256: cos(2*pi*t*k/512)/sqrt512 ; k>256 (f=k-256): -sin(2*pi*t*f/512)/sqrt512
// Wt[k][t] (bf16): irfft basis transposed: scale 1 for k=0,256 else 2, same trig as D.
__global__ __launch_bounds__(256) void k_gen_trig(float* __restrict__ D, ushort_t* __restrict__ Wt) {
    int id = blockIdx.x * 256 + threadIdx.x;   // 512*512
    int a = id >> 9;
    int c = id & 511;
    {   // D[t=a][k=c]
        int f = (c <= 256) ? c : (c - 256);
        int m = (a * f) & 511;
        float ang = (float)m * (6.283185307179586f / 512.0f);
        float v = (c <= 256) ? cosf(ang) : -sinf(ang);
        D[id] = v * RSQRT512;
    }
    {   // Wt[k=a][t=c]
        int f = (a <= 256) ? a : (a - 256);
        int m = (c * f) & 511;
        float ang = (float)m * (6.283185307179586f / 512.0f);
        float v = (a <= 256) ? cosf(ang) : -sinf(ang);
        float sc = (a == 0 || a == 256) ? 1.0f : 2.0f;
        Wt[id] = f2bf(v * sc * RSQRT512);
    }
}

// ---------------- K2: piecewise-linear region tables (single block, 256 thr) ----------------
// u = emb@w1; breakpoints bp_h = -b1_h/u_h; sort; scan regions r=0..256:
// AtabT[e*257+r] = sum_h c_h(r) u_h w2[h,e];  BtabT[e*257+r] = sum_h c_h(r) b1_h w2[h,e] + b2[e]
__global__ __launch_bounds__(256) void k_prep(const float* __restrict__ emb, const float* __restrict__ w1,
                                              const float* __restrict__ b1, const float* __restrict__ w2,
                                              const float* __restrict__ b2,
                                              float* __restrict__ AtabT, float* __restrict__ BtabT,
                                              float* __restrict__ bpkey_g) {
    __shared__ float u_s[256], b1_s[256], key_s[256];
    __shared__ int idx_s[256];
    int tid = threadIdx.x;
    float acc = 0.f;
    for (int e = 0; e < 128; ++e) acc += emb[e] * w1[e * 256 + tid];
    u_s[tid] = acc;
    float bb0 = b1[tid];
    b1_s[tid] = bb0;
    key_s[tid] = (acc == 0.f) ? INFINITY : (-bb0 / acc);
    idx_s[tid] = tid;
    __syncthreads();
    // bitonic sort 256 (ascending)
    for (int k = 2; k <= 256; k <<= 1) {
        for (int j = k >> 1; j > 0; j >>= 1) {
            int ixj = tid ^ j;
            if (ixj > tid) {
                bool up = ((tid & k) == 0);
                float a0 = key_s[tid], a1 = key_s[ixj];
                if ((a0 > a1) == up) {
                    key_s[tid] = a1; key_s[ixj] = a0;
                    int t0 = idx_s[tid]; idx_s[tid] = idx_s[ixj]; idx_s[ixj] = t0;
                }
            }
            __syncthreads();
        }
    }
    bpkey_g[tid] = key_s[tid];
    if (tid < 128) {
        int e = tid;
        float aA = 0.f, aB = 0.f;
        for (int h = 0; h < 256; ++h) {
            float uu = u_s[h], bbh = b1_s[h];
            float c = (uu < 0.f || (uu == 0.f && bbh >= 0.f)) ? 1.0f : 0.01f;
            float w = w2[h * 128 + e];
            aA += c * uu * w;
            aB += c * bbh * w;
        }
        aB += b2[e];
        AtabT[e * 257] = aA;
        BtabT[e * 257] = aB;
        for (int r = 1; r <= 256; ++r) {
            int h = idx_s[r - 1];
            float uu = u_s[h], bbh = b1_s[h];
            float w = w2[h * 128 + e];
            float sgn = (uu > 0.f) ? 0.99f : -0.99f;
            aA += sgn * uu * w;
            aB += sgn * bbh * w;
            AtabT[e * 257 + r] = aA;
            BtabT[e * 257 + r] = aB;
        }
    }
}

// ---------------- small f32 GEMM: C = [leaky](A@B + bias), row-major ----------------
template<bool LEAKY, bool BIAS>
__global__ __launch_bounds__(256) void k_gemm_f32(const float* __restrict__ A, const float* __restrict__ Bm,
                                                  const float* __restrict__ bias, float* __restrict__ C,
                                                  int M, int N, int K) {
    __shared__ float As[32][65], Bs[32][65];
    int ntiles = N >> 6;
    int m0 = (blockIdx.x / ntiles) << 6;
    int n0 = (blockIdx.x % ntiles) << 6;
    int tid = threadIdx.x;
    int ty = tid >> 4, tx = tid & 15;
    float acc[4][4] = {};
    for (int kb = 0; kb < K; kb += 32) {
        for (int i = 0; i < 8; ++i) {
            int idx = tid + i * 256;
            int r = idx >> 5, kk = idx & 31;
            As[kk][r] = A[(size_t)(m0 + r) * K + kb + kk];
        }
        for (int i = 0; i < 8; ++i) {
            int idx = tid + i * 256;
            int kk = idx >> 6, n = idx & 63;
            Bs[kk][n] = Bm[(size_t)(kb + kk) * N + n0 + n];
        }
        __syncthreads();
        for (int kk = 0; kk < 32; ++kk) {
            float a[4], b[4];
            for (int i = 0; i < 4; ++i) a[i] = As[kk][ty * 4 + i];
            for (int j = 0; j < 4; ++j) b[j] = Bs[kk][tx * 4 + j];
            for (int i = 0; i < 4; ++i)
                for (int j = 0; j < 4; ++j) acc[i][j] += a[i] * b[j];
        }
        __syncthreads();
    }
    for (int i = 0; i < 4; ++i)
        for (int j = 0; j < 4; ++j) {
            int n = n0 + tx * 4 + j;
            float v = acc[i][j];
            if (BIAS) v += bias[n];
            if (LEAKY) v = leaky_(v);
            C[(size_t)(m0 + ty * 4 + i) * N + n] = v;
        }
}

// ---------------- K8b: transpose fw1 [65536][256] f32 -> fw1T [32768 (j'=e*256+h)][512 (t)] bf16 ----------------
__global__ __launch_bounds__(256) void k_transpose_fw1(const float* __restrict__ fw1, ushort_t* __restrict__ fw1T) {
    __shared__ float tile[64][65];
    int bid = blockIdx.x;          // 8 * 512 = 4096
    int jt = bid & 511;
    int tt = bid >> 9;
    int t0 = tt << 6, j0 = jt << 6;
    int tid = threadIdx.x;
    for (int i = 0; i < 16; ++i) {
        int idx = tid + i * 256;
        int r = idx >> 6, cc = idx & 63;
        tile[r][cc] = fw1[(size_t)(t0 + r) * 32768 + j0 + cc];
    }
    __syncthreads();
    for (int i = 0; i < 16; ++i) {
        int idx = tid + i * 256;
        int r = idx >> 6, cc = idx & 63;
        fw1T[(size_t)(j0 + r) * 512 + t0 + cc] = f2bf(tile[cc][r]);
    }
}

// ---------------- bf16 MFMA GEMM (both operands K-contiguous: A[M][K], B[N][K]) ----------------
// MODE 0: K8  M2T = Wt @ fw1T^T : M=512(k), N=32768(j'=e*256+h), K=512(t)
//         scatter-store C[k,j'] -> M2T[h*65536 + e*512 + k] as bf16
// MODE 1: K9  h2 += Yp @ M2T^T : M=512(bn), N=256(h), K=65536(k'=e*512+k), split-K atomics
template<int MODE>
__global__ __launch_bounds__(256) void k_gemm_bf16(const ushort_t* __restrict__ A, const ushort_t* __restrict__ Bm,
                                                   void* __restrict__ C) {
    __shared__ ushort_t As[128 * 72];
    __shared__ ushort_t Bs[128 * 72];
    int tid = threadIdx.x;
    int lane = tid & 63, wid = tid >> 6;
    int wr = wid >> 1, wc = wid & 1;
    int m0, n0, k0, iters, ldK;
    if (MODE == 0) {
        int bid = blockIdx.x;           // 1024, XCD-grouped swizzle
        int xcd = bid & 7, j = bid >> 3;
        int mt = j & 3, nl = j >> 2;    // nl in [0,32)
        int nt = xcd * 32 + nl;
        m0 = mt * 128; n0 = nt * 128; k0 = 0; iters = 8; ldK = 512;
    } else {
        int bid = blockIdx.x;           // 256 = 32 kchunks * 4 mt * 2 nt
        int kchunk = bid >> 3;
        int mt = (bid >> 1) & 3, nt = bid & 1;
        m0 = mt * 128; n0 = nt * 128; k0 = kchunk * 2048; iters = 32; ldK = 65536;
    }
    f32x4 acc[4][4] = {};
    for (int kt = 0; kt < iters; ++kt) {
        int kb = k0 + kt * 64;
        __syncthreads();
        {
            uint4 va[4], vb[4];
            for (int i = 0; i < 4; ++i) {
                int q = tid + i * 256;
                int row = q >> 3, kc = (q & 7) << 3;
                va[i] = *(const uint4*)(A + (size_t)(m0 + row) * ldK + kb + kc);
                vb[i] = *(const uint4*)(Bm + (size_t)(n0 + row) * ldK + kb + kc);
            }
            for (int i = 0; i < 4; ++i) {
                int q = tid + i * 256;
                int row = q >> 3, kc = (q & 7) << 3;
                *(uint4*)&As[row * 72 + kc] = va[i];
                *(uint4*)&Bs[row * 72 + kc] = vb[i];
            }
        }
        __syncthreads();
        for (int ks = 0; ks < 2; ++ks) {
            short8 a[4], b[4];
            int kk = ks * 32 + (lane >> 4) * 8;
            for (int mi = 0; mi < 4; ++mi)
                a[mi] = *(const short8*)&As[(wr * 64 + mi * 16 + (lane & 15)) * 72 + kk];
            for (int ni = 0; ni < 4; ++ni)
                b[ni] = *(const short8*)&Bs[(wc * 64 + ni * 16 + (lane & 15)) * 72 + kk];
            for (int mi = 0; mi < 4; ++mi)
                for (int ni = 0; ni < 4; ++ni)
                    acc[mi][ni] = __builtin_amdgcn_mfma_f32_16x16x32_bf16(a[mi], b[ni], acc[mi][ni], 0, 0, 0);
        }
    }
    if (MODE == 0) {
        ushort_t* M2T = (ushort_t*)C;
        for (int mi = 0; mi < 4; ++mi)
            for (int ni = 0; ni < 4; ++ni) {
                int m = m0 + wr * 64 + mi * 16 + (lane >> 4) * 4;      // k index (4 consecutive via regs)
                int jp = n0 + wc * 64 + ni * 16 + (lane & 15);         // j' = e*256 + h
                int e = jp >> 8, h = jp & 255;
                size_t dst = ((size_t)h << 16) + ((size_t)e << 9) + m;
                ushort4 o;
                o.x = f2bf(acc[mi][ni][0]);
                o.y = f2bf(acc[mi][ni][1]);
                o.z = f2bf(acc[mi][ni][2]);
                o.w = f2bf(acc[mi][ni][3]);
                *(ushort4*)(M2T + dst) = o;
            }
    } else {
        float* h2 = (float*)C;
        for (int mi = 0; mi < 4; ++mi)
            for (int ni = 0; ni < 4; ++ni) {
                int mbase = m0 + wr * 64 + mi * 16 + (lane >> 4) * 4;
                int n = n0 + wc * 64 + ni * 16 + (lane & 15);
                for (int rg = 0; rg < 4; ++rg)
                    atomicAdd(h2 + (size_t)(mbase + rg) * 256 + n, acc[mi][ni][rg]);
            }
    }
}

// ---------------- K9b: G[k][h] = sum_e (1+emb[e]) * M2T[h][e][k] ----------------
__global__ __launch_bounds__(256) void k_reduce_G(const ushort_t* __restrict__ M2T, const float* __restrict__ emb,
                                                  float* __restrict__ G) {
    int h = blockIdx.x >> 1;                      // 512 blocks
    int k = ((blockIdx.x & 1) << 8) + threadIdx.x;
    float acc = 0.f;
    for (int e = 0; e < 128; ++e)
        acc += (1.f + emb[e]) * bf2f(M2T[((size_t)h << 16) + (e << 9) + k]);
    G[(size_t)k * 256 + h] = acc;
}

// ---------------- K7: assemble Y' [bn][e][k] bf16 = softshrink(s*A[r]+B[r]) + xnhat ----------------
__global__ __launch_bounds__(256) void k_assemble_Y(const float* __restrict__ s, const float* __restrict__ xnhat,
                                                    const float* __restrict__ AtabT, const float* __restrict__ BtabT,
                                                    const float* __restrict__ bpkey,
                                                    ushort_t* __restrict__ Yp) {
    __shared__ float bp_s[256];
    int bn = blockIdx.x >> 1;          // 1024 blocks
    int k0 = (blockIdx.x & 1) << 8;
    int tid = threadIdx.x;
    bp_s[tid] = bpkey[tid];
    __syncthreads();
    int k = k0 + tid;
    float sv = s[(size_t)bn * 512 + k];
    float xnh = xnhat[(size_t)bn * 512 + k];
    int lo = 0, hi = 256;
    while (lo < hi) { int mid = (lo + hi) >> 1; if (bp_s[mid] <= sv) lo = mid + 1; else hi = mid; }
    int r = lo;
    for (int e = 0; e < 128; ++e) {
        float y = sv * AtabT[e * 257 + r] + BtabT[e * 257 + r];
        y = (y > LAMBDA_) ? (y - LAMBDA_) : ((y < -LAMBDA_) ? (y + LAMBDA_) : 0.f);
        Yp[((size_t)bn * 128 + e) * 512 + k] = f2bf(y + xnh);
    }
}

// ---------------- K10: final: a=leaky(h2+h2b+fb1); out2=a@fw2+fb2; transposed store ----------------
__global__ __launch_bounds__(128) void k_final(const float* __restrict__ h2, const float* __restrict__ h2b,
                                               const float* __restrict__ fb1,
                                               const float* __restrict__ fw2, const float* __restrict__ fb2,
                                               float* __restrict__ out) {
    __shared__ float a_s[256];
    int bn = blockIdx.x;               // 512 blocks
    int tid = threadIdx.x;
    for (int i = tid; i < 256; i += 128)
        a_s[i] = leaky_(h2[(size_t)bn * 256 + i] + h2b[(size_t)bn * 256 + i] + fb1[i]);
    __syncthreads();
    if (tid < 96) {
        float acc = fb2[tid];
        for (int hh = 0; hh < 256; ++hh)
            acc += a_s[hh] * fw2[hh * 96 + tid];
        int b = bn >> 6, n = bn & 63;
        out[(size_t)(b * 96 + tid) * 64 + n] = acc;
    }
}

extern "C" void kernel_launch(void* const* d_in, const int* in_sizes, int n_in,
                              void* d_out, int out_size, void* d_ws, size_t ws_size,
                              hipStream_t stream) {
    const float* x   = (const float*)d_in[0];
    const float* emb = (const float*)d_in[1];
    const float* w1  = (const float*)d_in[2];
    const float* b1  = (const float*)d_in[3];
    const float* w2  = (const float*)d_in[4];
    const float* b2  = (const float*)d_in[5];
    const float* tw1 = (const float*)d_in[6];
    const float* tb1 = (const float*)d_in[7];
    const float* tw2 = (const float*)d_in[8];
    const float* tb2 = (const float*)d_in[9];
    const float* fw1 = (const float*)d_in[10];
    const float* fb1 = (const float*)d_in[11];
    const float* fw2 = (const float*)d_in[12];
    const float* fb2 = (const float*)d_in[13];
    float* out = (float*)d_out;

    char* W = (char*)d_ws;
    size_t off = 0;
    auto take = [&](size_t bytes) { size_t r = off; off += (bytes + 255) & ~(size_t)255; return r; };
    ushort_t* Yp   = (ushort_t*)(W + take(67108864));   // [512 bn][128 e][512 k] bf16
    ushort_t* fw1T = Yp;                                // alias: fw1T [32768][512] bf16, dead before Yp written
    ushort_t* M2T  = (ushort_t*)(W + take(33554432));   // [256 h][128 e][512 k] bf16
    float* xT      = (float*)(W + take(512 * 512 * 4));
    float* Dm      = (float*)(W + take(512 * 512 * 4));
    ushort_t* Wt   = (ushort_t*)(W + take(512 * 512 * 2));
    float* hx      = (float*)(W + take(512 * 256 * 4));
    float* xn      = (float*)(W + take(512 * 512 * 4));
    float* s       = (float*)(W + take(512 * 512 * 4));
    float* xnhat   = (float*)(W + take(512 * 512 * 4));
    float* AtabT   = (float*)(W + take(128 * 257 * 4));
    float* BtabT   = (float*)(W + take(128 * 257 * 4));
    float* bpkey   = (float*)(W + take(256 * 4));
    float* h2      = (float*)(W + take(512 * 256 * 4));
    float* h2b     = (float*)(W + take(512 * 256 * 4));
    float* G       = (float*)(W + take(512 * 256 * 4));
    (void)ws_size; (void)in_sizes; (void)n_in; (void)out_size;

    k_transpose_x<<<256, 256, 0, stream>>>(x, xT);
    k_gen_trig<<<1024, 256, 0, stream>>>(Dm, Wt);
    k_prep<<<1, 256, 0, stream>>>(emb, w1, b1, w2, b2, AtabT, BtabT, bpkey);
    // xn = MLP_time(x_noD):
    k_gemm_f32<true,  true ><<<32, 256, 0, stream>>>(xT, tw1, tb1, hx, 512, 256, 512);
    k_gemm_f32<false, true ><<<64, 256, 0, stream>>>(hx, tw2, tb2, xn, 512, 512, 256);
    // packed rfft of x_noD and xn:
    k_gemm_f32<false, false><<<64, 256, 0, stream>>>(xT, Dm, nullptr, s,     512, 512, 512);
    k_gemm_f32<false, false><<<64, 256, 0, stream>>>(xn, Dm, nullptr, xnhat, 512, 512, 512);
    // M2 = W^T-fold of fw1:
    k_transpose_fw1<<<4096, 256, 0, stream>>>(fw1, fw1T);
    k_gemm_bf16<0><<<1024, 256, 0, stream>>>(Wt, fw1T, M2T);
    k_reduce_G<<<512, 256, 0, stream>>>(M2T, emb, G);
    // spectral assembly (overwrites fw1T region -- must come after k_gemm_bf16<0>):
    k_assemble_Y<<<1024, 256, 0, stream>>>(s, xnhat, AtabT, BtabT, bpkey, Yp);
    // h2 = Yp @ M2T^T (split-K atomics) ; h2b = s @ G (exact f32 bias/xn-spectral path)
    hipMemsetAsync(h2, 0, 512 * 256 * 4, stream);
    k_gemm_bf16<1><<<256, 256, 0, stream>>>(Yp, M2T, h2);
    k_gemm_f32<false, false><<<32, 256, 0, stream>>>(s, G, nullptr, h2b, 512, 256, 512);
    k_final<<<512, 128, 0, stream>>>(h2, h2b, fb1, fw2, fb2, out);
}